// Round 1
// baseline (299.406 us; speedup 1.0000x reference)
//
#include <hip/hip_runtime.h>
#include <math.h>

#define BB 64
#define AA 8732
#define DD 85
#define GG 32
#define CC 81
#define TILE 64
#define NT 137   /* ceil(8732/64) */

// ---------------- workspace layout (bytes) ----------------
// match:       0          .. 2235392   (B*A int32)
// n_pos:       2235392    .. 2235648   (B int32)
// all_neg:     2235648    .. 4471040   (B*A float)
// partials:    4471040    .. 4506112   (B*NT float)
// batch_total: 4506112    .. 4506368   (B float)

__device__ __forceinline__ float smoothl1(float d) {
  float ad = fabsf(d);
  return ad < 1.0f ? 0.5f * d * d : ad - 0.5f;
}

// One block per batch: per-anchor best-GT (threshold), per-GT best anchor
// (forced match, ascending-g last-write-wins), then n_pos count.
__global__ __launch_bounds__(1024) void k_match(
    const float* __restrict__ anchors, const float* __restrict__ gt_boxes,
    const int* __restrict__ gt_counts, int* __restrict__ match,
    int* __restrict__ n_pos)
{
  const int b = blockIdx.x;
  const int tid = threadIdx.x;
  const int count = gt_counts[b];
  __shared__ float gx0[GG], gy0[GG], gx1[GG], gy1[GG], gar[GG];
  __shared__ int bestp[GG];
  __shared__ float wv[16];
  __shared__ int wi[16];

  if (tid < GG) {
    float4 gb = reinterpret_cast<const float4*>(gt_boxes)[b * GG + tid];
    float x0 = gb.x - gb.z * 0.5f, y0 = gb.y - gb.w * 0.5f;
    float x1 = gb.x + gb.z * 0.5f, y1 = gb.y + gb.w * 0.5f;
    gx0[tid] = x0; gy0[tid] = y0; gx1[tid] = x1; gy1[tid] = y1;
    gar[tid] = (x1 - x0) * (y1 - y0);
  }
  __syncthreads();

  // phase 1: per-anchor best GT (first-max wins, matching jnp.argmax)
  for (int a = tid; a < AA; a += blockDim.x) {
    float4 an = reinterpret_cast<const float4*>(anchors)[a];
    float ax0 = an.x - an.z * 0.5f, ay0 = an.y - an.w * 0.5f;
    float ax1 = an.x + an.z * 0.5f, ay1 = an.y + an.w * 0.5f;
    float aar = (ax1 - ax0) * (ay1 - ay0);
    float best = -1.0f; int bi = 0;
    for (int g = 0; g < count; ++g) {
      float iw = fmaxf(fminf(gx1[g], ax1) - fmaxf(gx0[g], ax0), 0.0f);
      float ih = fmaxf(fminf(gy1[g], ay1) - fmaxf(gy0[g], ay0), 0.0f);
      float inter = iw * ih;
      float iou = inter / (gar[g] + aar - inter);
      if (iou > best) { best = iou; bi = g; }
    }
    match[b * AA + a] = (best > 0.5f) ? bi : -1;
  }
  __syncthreads();

  // phase 2: per-GT best anchor (lowest index on ties, matching argmax)
  for (int g = 0; g < count; ++g) {
    float gx0g = gx0[g], gy0g = gy0[g], gx1g = gx1[g], gy1g = gy1[g], garg = gar[g];
    float bv = -2.0f; int bi = AA;
    for (int a = tid; a < AA; a += blockDim.x) {
      float4 an = reinterpret_cast<const float4*>(anchors)[a];
      float ax0 = an.x - an.z * 0.5f, ay0 = an.y - an.w * 0.5f;
      float ax1 = an.x + an.z * 0.5f, ay1 = an.y + an.w * 0.5f;
      float aar = (ax1 - ax0) * (ay1 - ay0);
      float iw = fmaxf(fminf(gx1g, ax1) - fmaxf(gx0g, ax0), 0.0f);
      float ih = fmaxf(fminf(gy1g, ay1) - fmaxf(gy0g, ay0), 0.0f);
      float inter = iw * ih;
      float iou = inter / (garg + aar - inter);
      if (iou > bv || (iou == bv && a < bi)) { bv = iou; bi = a; }
    }
    #pragma unroll
    for (int m = 1; m < 64; m <<= 1) {
      float ov = __shfl_xor(bv, m);
      int oi = __shfl_xor(bi, m);
      if (ov > bv || (ov == bv && oi < bi)) { bv = ov; bi = oi; }
    }
    if ((tid & 63) == 0) { wv[tid >> 6] = bv; wi[tid >> 6] = bi; }
    __syncthreads();
    if (tid == 0) {
      float fv = wv[0]; int fi = wi[0];
      for (int w = 1; w < 16; ++w)
        if (wv[w] > fv || (wv[w] == fv && wi[w] < fi)) { fv = wv[w]; fi = wi[w]; }
      bestp[g] = fi;
    }
    __syncthreads();
  }

  // forced-match scatter, ascending g = last-write-wins
  if (tid == 0) {
    for (int g = 0; g < count; ++g) match[b * AA + bestp[g]] = g;
  }
  __syncthreads();

  // n_pos after scatter
  int cnt = 0;
  for (int a = tid; a < AA; a += blockDim.x) cnt += (match[b * AA + a] >= 0) ? 1 : 0;
  #pragma unroll
  for (int m = 1; m < 64; m <<= 1) cnt += __shfl_xor(cnt, m);
  if ((tid & 63) == 0) wi[tid >> 6] = cnt;
  __syncthreads();
  if (tid == 0) {
    int t = 0;
    for (int w = 0; w < 16; ++w) t += wi[w];
    n_pos[b] = t;
  }
}

// Heavy pass: grid (NT, B), 256 threads. LDS-stage 64 contiguous rows of 85
// f32 (coalesced), then 4 threads/row do online softmax over 81 logits,
// capture x[0]/x[tgt], smooth-L1 for positives. Writes per-tile partial
// (loc + pos-CE, undivided) and all_neg per anchor.
__global__ __launch_bounds__(256) void k_loss(
    const float* __restrict__ pred, const float* __restrict__ anchors,
    const float* __restrict__ gt_boxes, const int* __restrict__ gt_labels,
    const int* __restrict__ match, float* __restrict__ all_neg,
    float* __restrict__ partials)
{
  const int b = blockIdx.y;
  const int tile = blockIdx.x;
  const int a0 = tile * TILE;
  const int nrows = min(TILE, AA - a0);
  __shared__ float rows[TILE * DD];
  __shared__ float wsum[4];

  const float* src = pred + ((size_t)b * AA + a0) * DD;
  const int total = nrows * DD;
  for (int i = threadIdx.x; i < total; i += 256) rows[i] = src[i];
  __syncthreads();

  const int r = threadIdx.x >> 2;
  const int sub = threadIdx.x & 3;
  float acc = 0.0f;
  if (r < nrows) {
    const int a = a0 + r;
    const int m = match[b * AA + a];
    int tgt = 0;
    if (m >= 0) tgt = gt_labels[b * GG + m] + 1;

    float mx = -INFINITY, s = 0.0f, x0 = -INFINITY, xt = -INFINITY;
    for (int cc = sub; cc < CC; cc += 4) {
      float x = rows[r * DD + 4 + cc];
      if (cc == 0)   x0 = x;
      if (cc == tgt) xt = x;
      if (x > mx) { s = s * expf(mx - x) + 1.0f; mx = x; }
      else        { s += expf(x - mx); }
    }
    // combine the 4 sub-lane partials (lanes are an aligned group of 4)
    #pragma unroll
    for (int msk = 1; msk <= 2; msk <<= 1) {
      float om  = __shfl_xor(mx, msk);
      float os  = __shfl_xor(s,  msk);
      float ox0 = __shfl_xor(x0, msk);
      float oxt = __shfl_xor(xt, msk);
      if (om > mx) { s = s * expf(mx - om) + os; mx = om; }
      else         { s += os * expf(om - mx); }
      x0 = fmaxf(x0, ox0);
      xt = fmaxf(xt, oxt);
    }
    float lse = mx + logf(s);

    if (sub == 0) {
      if (m >= 0) {
        float cls_ce = lse - xt;
        float4 an = reinterpret_cast<const float4*>(anchors)[a];
        float4 gb = reinterpret_cast<const float4*>(gt_boxes)[b * GG + m];
        float tx = (gb.x - an.x) / an.z;
        float ty = (gb.y - an.y) / an.w;
        float tw = logf(gb.z) - logf(an.z);
        float th = logf(gb.w) - logf(an.w);
        acc = smoothl1(rows[r * DD + 0] - tx)
            + smoothl1(rows[r * DD + 1] - ty)
            + smoothl1(rows[r * DD + 2] - tw)
            + smoothl1(rows[r * DD + 3] - th)
            + cls_ce;
        all_neg[b * AA + a] = 0.0f;
      } else {
        float ce = lse - x0;   // tgt==0 for negatives, so cls_ce == neg_ce
        all_neg[b * AA + a] = fmaxf(ce, 0.0f);
      }
    }
  }

  // block-reduce acc (fixed order → deterministic)
  #pragma unroll
  for (int msk = 1; msk < 64; msk <<= 1) acc += __shfl_xor(acc, msk);
  if ((threadIdx.x & 63) == 0) wsum[threadIdx.x >> 6] = acc;
  __syncthreads();
  if (threadIdx.x == 0)
    partials[b * NT + tile] = (wsum[0] + wsum[1]) + (wsum[2] + wsum[3]);
}

// Per-batch top-K sum via bit-pattern binary search over non-negative floats.
__global__ __launch_bounds__(1024) void k_select(
    const float* __restrict__ all_neg, const float* __restrict__ partials,
    const int* __restrict__ n_pos, float* __restrict__ batch_total)
{
  const int b = blockIdx.x;
  __shared__ float v[AA];
  __shared__ float wf[16];
  __shared__ int wc[16];

  const float4* src = reinterpret_cast<const float4*>(all_neg + (size_t)b * AA);
  for (int i = threadIdx.x; i < AA / 4; i += blockDim.x)
    reinterpret_cast<float4*>(v)[i] = src[i];
  __syncthreads();

  const int np = n_pos[b];
  const int K = min(3 * np, AA - 1);

  // find t* = K-th largest value (values >= 0, so uint bits are monotone)
  unsigned lo = 0u, hi = 0x7f7fffffu;
  while (lo < hi) {
    unsigned mid = lo + (hi - lo + 1u) / 2u;
    float T = __uint_as_float(mid);
    int c = 0;
    for (int i = threadIdx.x; i < AA; i += blockDim.x) c += (v[i] >= T) ? 1 : 0;
    #pragma unroll
    for (int m = 1; m < 64; m <<= 1) c += __shfl_xor(c, m);
    if ((threadIdx.x & 63) == 0) wc[threadIdx.x >> 6] = c;
    __syncthreads();
    int tot = 0;
    #pragma unroll
    for (int w = 0; w < 16; ++w) tot += wc[w];
    if (tot >= K) lo = mid; else hi = mid - 1u;
    __syncthreads();
  }
  const float tstar = __uint_as_float(lo);

  float ssum = 0.0f; int cgt = 0;
  for (int i = threadIdx.x; i < AA; i += blockDim.x) {
    float x = v[i];
    if (x > tstar) { ssum += x; cgt += 1; }
  }
  #pragma unroll
  for (int m = 1; m < 64; m <<= 1) {
    ssum += __shfl_xor(ssum, m);
    cgt  += __shfl_xor(cgt, m);
  }
  if ((threadIdx.x & 63) == 0) { wf[threadIdx.x >> 6] = ssum; wc[threadIdx.x >> 6] = cgt; }
  __syncthreads();
  if (threadIdx.x == 0) {
    float S = 0.0f; int Cg = 0;
    for (int w = 0; w < 16; ++w) { S += wf[w]; Cg += wc[w]; }
    float neg_sum = S + (float)(K - Cg) * tstar;  // ties at t* are negatives (value t*)
    float ps = 0.0f;
    for (int t = 0; t < NT; ++t) ps += partials[b * NT + t];
    batch_total[b] = (ps + neg_sum) / (float)np;
  }
}

__global__ void k_final(const float* __restrict__ batch_total,
                        float* __restrict__ out)
{
  if (threadIdx.x == 0) {
    float s = 0.0f;
    for (int b = 0; b < BB; ++b) s += batch_total[b];
    out[0] = s;
  }
}

extern "C" void kernel_launch(void* const* d_in, const int* in_sizes, int n_in,
                              void* d_out, int out_size, void* d_ws, size_t ws_size,
                              hipStream_t stream) {
  (void)in_sizes; (void)n_in; (void)out_size; (void)ws_size;
  const float* pred     = (const float*)d_in[0];
  const float* anchors  = (const float*)d_in[1];
  const float* gt_boxes = (const float*)d_in[2];
  const int*   gt_labels = (const int*)d_in[3];
  const int*   gt_counts = (const int*)d_in[4];

  char* ws = (char*)d_ws;
  int*   match       = (int*)(ws + 0);
  int*   n_pos       = (int*)(ws + 2235392);
  float* all_neg     = (float*)(ws + 2235648);
  float* partials    = (float*)(ws + 4471040);
  float* batch_total = (float*)(ws + 4506112);
  float* out = (float*)d_out;

  hipLaunchKernelGGL(k_match, dim3(BB), dim3(1024), 0, stream,
                     anchors, gt_boxes, gt_counts, match, n_pos);
  hipLaunchKernelGGL(k_loss, dim3(NT, BB), dim3(256), 0, stream,
                     pred, anchors, gt_boxes, gt_labels, match, all_neg, partials);
  hipLaunchKernelGGL(k_select, dim3(BB), dim3(1024), 0, stream,
                     all_neg, partials, n_pos, batch_total);
  hipLaunchKernelGGL(k_final, dim3(1), dim3(1), 0, stream, batch_total, out);
}

// Round 2
// 136.031 us; speedup vs baseline: 2.2010x; 2.2010x over previous
//
#include <hip/hip_runtime.h>
#include <math.h>

#define BB 64
#define AA 8732
#define DD 85
#define GG 32
#define CC 81
#define TILE 64
#define NT 137   /* ceil(8732/64) */

// ---------------- workspace layout (bytes) ----------------
// match:       0          .. 2235392   (B*A int32)
// n_pos:       2235392    .. 2235648   (B int32)
// all_neg:     2235648    .. 4471040   (B*A float)
// partials:    4471040    .. 4506112   (B*NT float)  [bestp aliased here pre-k_loss]
// batch_total: 4506112    .. 4506368   (B float)

__device__ __forceinline__ float smoothl1(float d) {
  float ad = fabsf(d);
  return ad < 1.0f ? 0.5f * d * d : ad - 0.5f;
}

// ---- match stage A: per-anchor best GT (threshold 0.5), flat grid ----
// grid (ceil(A/256), B), 256 threads; one thread = one anchor.
__global__ __launch_bounds__(256) void k_match_anchor(
    const float* __restrict__ anchors, const float* __restrict__ gt_boxes,
    const int* __restrict__ gt_counts, int* __restrict__ match)
{
  const int b = blockIdx.y;
  const int a = blockIdx.x * 256 + threadIdx.x;
  const int count = gt_counts[b];
  __shared__ float gx0[GG], gy0[GG], gx1[GG], gy1[GG], gar[GG];

  if (threadIdx.x < GG) {
    float4 gb = reinterpret_cast<const float4*>(gt_boxes)[b * GG + threadIdx.x];
    float x0 = gb.x - gb.z * 0.5f, y0 = gb.y - gb.w * 0.5f;
    float x1 = gb.x + gb.z * 0.5f, y1 = gb.y + gb.w * 0.5f;
    gx0[threadIdx.x] = x0; gy0[threadIdx.x] = y0;
    gx1[threadIdx.x] = x1; gy1[threadIdx.x] = y1;
    gar[threadIdx.x] = (x1 - x0) * (y1 - y0);
  }
  __syncthreads();
  if (a >= AA) return;

  float4 an = reinterpret_cast<const float4*>(anchors)[a];
  float ax0 = an.x - an.z * 0.5f, ay0 = an.y - an.w * 0.5f;
  float ax1 = an.x + an.z * 0.5f, ay1 = an.y + an.w * 0.5f;
  float aar = (ax1 - ax0) * (ay1 - ay0);
  float best = -1.0f; int bi = 0;
  for (int g = 0; g < count; ++g) {
    float iw = fmaxf(fminf(gx1[g], ax1) - fmaxf(gx0[g], ax0), 0.0f);
    float ih = fmaxf(fminf(gy1[g], ay1) - fmaxf(gy0[g], ay0), 0.0f);
    float inter = iw * ih;
    float iou = inter / (gar[g] + aar - inter);
    if (iou > best) { best = iou; bi = g; }  // first max wins (argmax semantics)
  }
  match[b * AA + a] = (best > 0.5f) ? bi : -1;
}

// ---- match stage B: per-(b,g) best anchor (forced match argmax) ----
// grid (G, B), 256 threads; block reduces over all 8732 anchors.
__global__ __launch_bounds__(256) void k_match_gt(
    const float* __restrict__ anchors, const float* __restrict__ gt_boxes,
    const int* __restrict__ gt_counts, int* __restrict__ bestp)
{
  const int g = blockIdx.x;
  const int b = blockIdx.y;
  if (g >= gt_counts[b]) return;

  float4 gb = reinterpret_cast<const float4*>(gt_boxes)[b * GG + g];
  const float gx0 = gb.x - gb.z * 0.5f, gy0 = gb.y - gb.w * 0.5f;
  const float gx1 = gb.x + gb.z * 0.5f, gy1 = gb.y + gb.w * 0.5f;
  const float gar = (gx1 - gx0) * (gy1 - gy0);

  float bv = -2.0f; int bi = AA;
  for (int a = threadIdx.x; a < AA; a += 256) {
    float4 an = reinterpret_cast<const float4*>(anchors)[a];
    float ax0 = an.x - an.z * 0.5f, ay0 = an.y - an.w * 0.5f;
    float ax1 = an.x + an.z * 0.5f, ay1 = an.y + an.w * 0.5f;
    float aar = (ax1 - ax0) * (ay1 - ay0);
    float iw = fmaxf(fminf(gx1, ax1) - fmaxf(gx0, ax0), 0.0f);
    float ih = fmaxf(fminf(gy1, ay1) - fmaxf(gy0, ay0), 0.0f);
    float inter = iw * ih;
    float iou = inter / (gar + aar - inter);
    if (iou > bv || (iou == bv && a < bi)) { bv = iou; bi = a; }
  }
  __shared__ float wv[4];
  __shared__ int wi[4];
  #pragma unroll
  for (int m = 1; m < 64; m <<= 1) {
    float ov = __shfl_xor(bv, m);
    int   oi = __shfl_xor(bi, m);
    if (ov > bv || (ov == bv && oi < bi)) { bv = ov; bi = oi; }
  }
  if ((threadIdx.x & 63) == 0) { wv[threadIdx.x >> 6] = bv; wi[threadIdx.x >> 6] = bi; }
  __syncthreads();
  if (threadIdx.x == 0) {
    float fv = wv[0]; int fi = wi[0];
    #pragma unroll
    for (int w = 1; w < 4; ++w)
      if (wv[w] > fv || (wv[w] == fv && wi[w] < fi)) { fv = wv[w]; fi = wi[w]; }
    bestp[b * GG + g] = fi;
  }
}

// ---- match stage C: forced scatter (ascending g = last-write-wins) + n_pos ----
__global__ __launch_bounds__(256) void k_scatter(
    const int* __restrict__ gt_counts, const int* __restrict__ bestp,
    int* __restrict__ match, int* __restrict__ n_pos)
{
  const int b = blockIdx.x;
  const int count = gt_counts[b];
  if (threadIdx.x == 0) {
    for (int g = 0; g < count; ++g) match[b * AA + bestp[b * GG + g]] = g;
  }
  __syncthreads();
  int cnt = 0;
  for (int a = threadIdx.x; a < AA; a += 256) cnt += (match[b * AA + a] >= 0) ? 1 : 0;
  __shared__ int wc[4];
  #pragma unroll
  for (int m = 1; m < 64; m <<= 1) cnt += __shfl_xor(cnt, m);
  if ((threadIdx.x & 63) == 0) wc[threadIdx.x >> 6] = cnt;
  __syncthreads();
  if (threadIdx.x == 0) n_pos[b] = wc[0] + wc[1] + wc[2] + wc[3];
}

// ---- heavy pass: per-anchor softmax CE + smooth-L1, 190MB single read ----
__global__ __launch_bounds__(256) void k_loss(
    const float* __restrict__ pred, const float* __restrict__ anchors,
    const float* __restrict__ gt_boxes, const int* __restrict__ gt_labels,
    const int* __restrict__ match, float* __restrict__ all_neg,
    float* __restrict__ partials)
{
  const int b = blockIdx.y;
  const int tile = blockIdx.x;
  const int a0 = tile * TILE;
  const int nrows = min(TILE, AA - a0);
  __shared__ float rows[TILE * DD];
  __shared__ float wsum[4];

  const float* src = pred + ((size_t)b * AA + a0) * DD;
  const int n4 = (nrows * DD) >> 2;   // nrows*85 is divisible by 4 for 64 and 28
  const float4* src4 = reinterpret_cast<const float4*>(src);
  float4* dst4 = reinterpret_cast<float4*>(rows);
  for (int i = threadIdx.x; i < n4; i += 256) dst4[i] = src4[i];
  __syncthreads();

  const int r = threadIdx.x >> 2;
  const int sub = threadIdx.x & 3;
  float acc = 0.0f;
  if (r < nrows) {
    const int a = a0 + r;
    const int m = match[b * AA + a];
    int tgt = 0;
    if (m >= 0) tgt = gt_labels[b * GG + m] + 1;

    float mx = -INFINITY, s = 0.0f, x0 = -INFINITY, xt = -INFINITY;
    for (int cc = sub; cc < CC; cc += 4) {
      float x = rows[r * DD + 4 + cc];
      if (cc == 0)   x0 = x;
      if (cc == tgt) xt = x;
      if (x > mx) { s = s * expf(mx - x) + 1.0f; mx = x; }
      else        { s += expf(x - mx); }
    }
    #pragma unroll
    for (int msk = 1; msk <= 2; msk <<= 1) {
      float om  = __shfl_xor(mx, msk);
      float os  = __shfl_xor(s,  msk);
      float ox0 = __shfl_xor(x0, msk);
      float oxt = __shfl_xor(xt, msk);
      if (om > mx) { s = s * expf(mx - om) + os; mx = om; }
      else         { s += os * expf(om - mx); }
      x0 = fmaxf(x0, ox0);
      xt = fmaxf(xt, oxt);
    }
    float lse = mx + logf(s);

    if (sub == 0) {
      if (m >= 0) {
        float cls_ce = lse - xt;
        float4 an = reinterpret_cast<const float4*>(anchors)[a];
        float4 gb = reinterpret_cast<const float4*>(gt_boxes)[b * GG + m];
        float tx = (gb.x - an.x) / an.z;
        float ty = (gb.y - an.y) / an.w;
        float tw = logf(gb.z) - logf(an.z);
        float th = logf(gb.w) - logf(an.w);
        acc = smoothl1(rows[r * DD + 0] - tx)
            + smoothl1(rows[r * DD + 1] - ty)
            + smoothl1(rows[r * DD + 2] - tw)
            + smoothl1(rows[r * DD + 3] - th)
            + cls_ce;
        all_neg[b * AA + a] = 0.0f;
      } else {
        float ce = lse - x0;   // tgt==0 for negatives
        all_neg[b * AA + a] = fmaxf(ce, 0.0f);
      }
    }
  }

  #pragma unroll
  for (int msk = 1; msk < 64; msk <<= 1) acc += __shfl_xor(acc, msk);
  if ((threadIdx.x & 63) == 0) wsum[threadIdx.x >> 6] = acc;
  __syncthreads();
  if (threadIdx.x == 0)
    partials[b * NT + tile] = (wsum[0] + wsum[1]) + (wsum[2] + wsum[3]);
}

// ---- per-batch top-K sum via 4-round radix select (exact K-th largest) ----
__global__ __launch_bounds__(1024) void k_select(
    const float* __restrict__ all_neg, const float* __restrict__ partials,
    const int* __restrict__ n_pos, float* __restrict__ batch_total)
{
  const int b = blockIdx.x;
  __shared__ unsigned u[AA];
  __shared__ int hist[256];
  __shared__ int gsum[64];
  __shared__ unsigned sh_pref;
  __shared__ int sh_k;
  __shared__ float wf[16];
  __shared__ int wc[16];

  const uint4* src = reinterpret_cast<const uint4*>(all_neg + (size_t)b * AA);
  for (int i = threadIdx.x; i < AA / 4; i += 1024)
    reinterpret_cast<uint4*>(u)[i] = src[i];
  __syncthreads();

  const int np = n_pos[b];
  const int K = min(3 * np, AA - 1);

  unsigned prefix = 0;
  int kk = K;
  for (int shift = 24; shift >= 0; shift -= 8) {
    if (threadIdx.x < 256) hist[threadIdx.x] = 0;
    __syncthreads();
    const unsigned hmask = (shift == 24) ? 0u : (0xFFFFFFFFu << (shift + 8));
    for (int i = threadIdx.x; i < AA; i += 1024) {
      unsigned x = u[i];
      if ((x & hmask) == prefix)
        atomicAdd(&hist[(x >> shift) & 255], 1);
    }
    __syncthreads();
    if (threadIdx.x < 64) {
      int base = 255 - 4 * threadIdx.x;
      gsum[threadIdx.x] = hist[base] + hist[base - 1] + hist[base - 2] + hist[base - 3];
    }
    __syncthreads();
    if (threadIdx.x == 0) {
      int cum = 0, chosen = 0;
      const int kv = kk;
      for (int t = 0; t < 64; ++t) {
        int gs = gsum[t];
        if (cum + gs < kv) { cum += gs; continue; }
        for (int bin = 255 - 4 * t; bin >= 252 - 4 * t; --bin) {
          int h = hist[bin];
          if (cum + h >= kv) { chosen = bin; break; }
          cum += h;
        }
        break;
      }
      sh_pref = prefix | ((unsigned)chosen << shift);
      sh_k = kk - cum;          // rank among values sharing this prefix+byte
    }
    __syncthreads();
    prefix = sh_pref;
    kk = sh_k;
    __syncthreads();
  }
  const float tstar = __uint_as_float(prefix);   // exact K-th largest value

  float ssum = 0.0f; int cgt = 0;
  for (int i = threadIdx.x; i < AA; i += 1024) {
    float x = __uint_as_float(u[i]);
    if (x > tstar) { ssum += x; cgt += 1; }
  }
  #pragma unroll
  for (int m = 1; m < 64; m <<= 1) {
    ssum += __shfl_xor(ssum, m);
    cgt  += __shfl_xor(cgt, m);
  }
  if ((threadIdx.x & 63) == 0) { wf[threadIdx.x >> 6] = ssum; wc[threadIdx.x >> 6] = cgt; }
  __syncthreads();
  if (threadIdx.x == 0) {
    float S = 0.0f; int Cg = 0;
    for (int w = 0; w < 16; ++w) { S += wf[w]; Cg += wc[w]; }
    float neg_sum = S + (float)(K - Cg) * tstar;
    float ps = 0.0f;
    for (int t = 0; t < NT; ++t) ps += partials[b * NT + t];
    batch_total[b] = (ps + neg_sum) / (float)np;
  }
}

__global__ void k_final(const float* __restrict__ batch_total,
                        float* __restrict__ out)
{
  if (threadIdx.x == 0) {
    float s = 0.0f;
    for (int b = 0; b < BB; ++b) s += batch_total[b];
    out[0] = s;
  }
}

extern "C" void kernel_launch(void* const* d_in, const int* in_sizes, int n_in,
                              void* d_out, int out_size, void* d_ws, size_t ws_size,
                              hipStream_t stream) {
  (void)in_sizes; (void)n_in; (void)out_size; (void)ws_size;
  const float* pred      = (const float*)d_in[0];
  const float* anchors   = (const float*)d_in[1];
  const float* gt_boxes  = (const float*)d_in[2];
  const int*   gt_labels = (const int*)d_in[3];
  const int*   gt_counts = (const int*)d_in[4];

  char* ws = (char*)d_ws;
  int*   match       = (int*)(ws + 0);
  int*   n_pos       = (int*)(ws + 2235392);
  float* all_neg     = (float*)(ws + 2235648);
  float* partials    = (float*)(ws + 4471040);
  float* batch_total = (float*)(ws + 4506112);
  // bestp (B*G int = 8KB) aliases the partials region: consumed by k_scatter
  // strictly before k_loss writes partials (same stream, ordered).
  int*   bestp       = (int*)(ws + 4471040);
  float* out = (float*)d_out;

  hipLaunchKernelGGL(k_match_anchor, dim3((AA + 255) / 256, BB), dim3(256), 0, stream,
                     anchors, gt_boxes, gt_counts, match);
  hipLaunchKernelGGL(k_match_gt, dim3(GG, BB), dim3(256), 0, stream,
                     anchors, gt_boxes, gt_counts, bestp);
  hipLaunchKernelGGL(k_scatter, dim3(BB), dim3(256), 0, stream,
                     gt_counts, bestp, match, n_pos);
  hipLaunchKernelGGL(k_loss, dim3(NT, BB), dim3(256), 0, stream,
                     pred, anchors, gt_boxes, gt_labels, match, all_neg, partials);
  hipLaunchKernelGGL(k_select, dim3(BB), dim3(1024), 0, stream,
                     all_neg, partials, n_pos, batch_total);
  hipLaunchKernelGGL(k_final, dim3(1), dim3(1), 0, stream, batch_total, out);
}